// Round 9
// baseline (273.661 us; speedup 1.0000x reference)
//
#include <hip/hip_runtime.h>

// N=2048, D=512, A=64, NQ=8, G1=G2=8, A1=128.
// Algebra (no softmax): ctx = q (K^T V)/sqrt(a) => per-group fold:
//   S[g]=(xWk+bk)^T(xWv+bv)/sqrt(a); M[g]=sum_q Wq S Wo_q; o[g]=x M[g]+c[g];
//   tier2 same; Wo2p[g]=Wo2[g]@Wo precomputed => M2p = T2@Wo2p,
//   c2p = r2@Wo2p + (bo2@Wo + bo).
// R18 post-mortem: 259.7 ~= R15's 257.3 (small-first neutral). All stages
//   <40us; remaining time distributed over 11 serial stages.
// R19: (a) prep vectorized — mode-1 fp32->bf16 now 64B/thread (2x bf16x8
//      stores), mode-0 transpose 4 tiles/block, mode-4 zero 64B/thread:
//      grid ~15.7K -> ~3.8K blocks (G13: memory-bound needs wide lanes);
//      (b) stage 2 ksplit 8->32 (grid 256->1024) and stage 7 ksplit 16->32
//      (grid 128->256): these were 1 / 0.5 blocks per CU — TLP-starved;
//      nT=1 loses prefetch but 4 blocks/CU TLP replaces it.
// Carried: BK=64 XOR-swizzled 2-phase gemm_block (R15), ss_gemm (R13),
//   mode-2 swapped-operand transposed store (R14), small-first (R18).

typedef __bf16 bf16x8 __attribute__((ext_vector_type(8)));
typedef float  f32x4  __attribute__((ext_vector_type(4)));

struct PD { const float* s; void* d; int R, C, Bc, mode, blocks; };
struct PArgs { PD p[20]; int n; };

struct MA {
    const float *x,*bq1,*bo1,*bq2,*bo2,*bo;
    float* out;
    __bf16 *xb,*Wk1t,*Wv1t,*Wq1b,*Wo1t,*Wk2t,*Wv2t,*Wq2b,*Wo2b,*Wot;
    __bf16 *Ktb,*Vtb,*T1b,*M1t,*o1b,*K2tb,*V2tb,*T2b,*Wo2pT,*M2pt;
    float *STf1,*STf2,*kvb1,*kvb2,*c1,*c2p,*bo2p;
    PArgs pa;
    int prepTot;
};

// ---------------- single-shot-K GEMM (K fits LDS; one barrier) -------------
template<int BM, int BN, int KK>
__device__ __forceinline__ void ss_gemm(void* smv,
    const __bf16* __restrict__ A, const float* __restrict__ Bf,
    __bf16* __restrict__ C, long aG, long bG, long cG, int cD, int cQ, int vb)
{
    constexpr int MT = BM / 32, NT = BN / 32, KS = KK / 32;
    constexpr int ACH = (KK * 2) / 16;
    constexpr int ABYTES = BM * KK * 2;
    constexpr int AITER = ABYTES / 16 / 256;
    constexpr int ROWB = KK * 2;
    constexpr int F4PT = (BN * KK) / 4 / 256;
    constexpr int TPR  = (KK / 4) / F4PT;

    char* smc = (char*)smv;
    int g = vb >> 6, rb = vb & 63;
    A  += g * aG + (long)rb * BM * KK;
    Bf += g * bG;
    C  += g * cG;

    int tid = threadIdx.x, wave = tid >> 6, lane = tid & 63;
    int mrow = lane & 15, quad = lane >> 4;

    #pragma unroll
    for (int i = 0; i < AITER; ++i) {
        int c = tid + i * 256;
        int row = c / ACH, cp = c % ACH;
        int cg = cp ^ (row & 7);
        __builtin_amdgcn_global_load_lds(
            (const __attribute__((address_space(1))) void*)(A + (long)row * KK + cg * 8),
            (__attribute__((address_space(3))) void*)(smc + c * 16),
            16, 0, 0);
    }
    {
        int brow = tid / TPR, bseg = tid % TPR;
        const float4* bsrc = (const float4*)(Bf + (long)brow * KK + bseg * (KK / TPR));
        int cbase = (bseg * (KK / TPR)) >> 3;
        int bx7 = brow & 7;
        char* bls = smc + ABYTES + (long)brow * ROWB;
        #pragma unroll
        for (int j = 0; j < F4PT / 2; ++j) {
            float4 f0 = bsrc[2 * j], f1 = bsrc[2 * j + 1];
            bf16x8 v = {(__bf16)f0.x, (__bf16)f0.y, (__bf16)f0.z, (__bf16)f0.w,
                        (__bf16)f1.x, (__bf16)f1.y, (__bf16)f1.z, (__bf16)f1.w};
            *(bf16x8*)(bls + (((cbase + j) ^ bx7) << 4)) = v;
        }
    }
    __syncthreads();

    int wm = (wave >> 1) * (BM / 2), wn = (wave & 1) * (BN / 2);
    f32x4 acc[MT][NT];
    #pragma unroll
    for (int i = 0; i < MT; ++i)
        #pragma unroll
        for (int j = 0; j < NT; ++j)
            acc[i][j] = f32x4{0.f, 0.f, 0.f, 0.f};

    #pragma unroll
    for (int ks = 0; ks < KS; ++ks) {
        bf16x8 af[MT], bv[NT];
        #pragma unroll
        for (int mt = 0; mt < MT; ++mt) {
            int r = wm + mt * 16 + mrow;
            af[mt] = *(const bf16x8*)(smc + (long)r * ROWB
                        + (((ks * 4 + quad) ^ (r & 7)) << 4));
        }
        #pragma unroll
        for (int nt = 0; nt < NT; ++nt) {
            int r = wn + nt * 16 + mrow;
            bv[nt] = *(const bf16x8*)(smc + ABYTES + (long)r * ROWB
                        + (((ks * 4 + quad) ^ (r & 7)) << 4));
        }
        #pragma unroll
        for (int mt = 0; mt < MT; ++mt)
            #pragma unroll
            for (int nt = 0; nt < NT; ++nt)
                acc[mt][nt] = __builtin_amdgcn_mfma_f32_16x16x32_bf16(
                    af[mt], bv[nt], acc[mt][nt], 0, 0, 0);
    }

    #pragma unroll
    for (int mt = 0; mt < MT; ++mt) {
        #pragma unroll
        for (int r4 = 0; r4 < 4; ++r4) {
            int rl = wm + mt * 16 + quad * 4 + r4;
            int ra = rb * BM + rl;
            int q = ra >> 9, d = ra & 511;
            #pragma unroll
            for (int nt = 0; nt < NT; ++nt) {
                int col = wn + nt * 16 + mrow;
                C[(long)d * cD + q * cQ + col] = (__bf16)acc[mt][nt][r4];
            }
        }
    }
}

// ---------------- bf16 MFMA GEMM block, C = alpha*(A.B^T) (+bias) ----------
// MODE: 0=f32, 1=bf16, 2=bf16 transposed (swapped MFMA operands), 3=f32 atomic.
// BK=64 2-phase XOR-swizzled pipeline (R15).
template<int BM, int BN, int MODE>
__device__ __forceinline__ void gemm_block(void* smv,
    const __bf16* __restrict__ A, const __bf16* __restrict__ B,
    const float* __restrict__ bias, void* __restrict__ Cv,
    int K, int lda, int ldb, int ldc, int divq, int ksplit,
    long aOut, long aIn, long bOut, long bIn, long cOut, long cIn,
    long biasOut, long biasIn, int hasBias, float alpha,
    int bx, int by, int bz)
{
    constexpr int MT = BM / 32, NT = BN / 32;
    constexpr int ROWB = 128;
    constexpr int HALF = (BM + BN) * ROWB;
    constexpr int AOPS = BM * 8 / 256;
    constexpr int BOPS = BN * 8 / 256;

    char* smc = (char*)smv;

    int b  = bz / ksplit, ks = bz - b * ksplit;
    int go = b / divq,  gi = b - go * divq;
    A += go * aOut + gi * aIn;
    B += go * bOut + gi * bIn;
    long cBase = go * cOut + gi * cIn;
    if (hasBias) bias += go * biasOut + gi * biasIn;

    int kChunk = K / ksplit;
    int k0 = ks * kChunk;
    int nT = kChunk / 64;

    int bm = by * BM, bn = bx * BN;
    int tid = threadIdx.x, wave = tid >> 6, lane = tid & 63;
    int wm = (wave >> 1) * (BM / 2), wn = (wave & 1) * (BN / 2);
    int mrow = lane & 15, quad = lane >> 4;

    f32x4 acc[MT][NT];
    #pragma unroll
    for (int i = 0; i < MT; ++i)
        #pragma unroll
        for (int j = 0; j < NT; ++j)
            acc[i][j] = f32x4{0.f, 0.f, 0.f, 0.f};

    auto issueAB = [&](int buf, int kk) {
        char* base = smc + buf * HALF;
        #pragma unroll
        for (int t = 0; t < AOPS; ++t) {
            int c = tid + t * 256;
            int row = c >> 3, cp = c & 7;
            int cg = cp ^ (row & 7);
            __builtin_amdgcn_global_load_lds(
                (const __attribute__((address_space(1))) void*)
                    (A + (long)(bm + row) * lda + kk + cg * 8),
                (__attribute__((address_space(3))) void*)(base + c * 16),
                16, 0, 0);
        }
        char* bbase = base + BM * ROWB;
        #pragma unroll
        for (int t = 0; t < BOPS; ++t) {
            int c = tid + t * 256;
            int row = c >> 3, cp = c & 7;
            int cg = cp ^ (row & 7);
            __builtin_amdgcn_global_load_lds(
                (const __attribute__((address_space(1))) void*)
                    (B + (long)(bn + row) * ldb + kk + cg * 8),
                (__attribute__((address_space(3))) void*)(bbase + c * 16),
                16, 0, 0);
        }
    };

    issueAB(0, k0);
    __syncthreads();

    int cur = 0;
    for (int t = 0; t < nT; ++t) {
        if (t + 1 < nT) issueAB(cur ^ 1, k0 + (t + 1) * 64);

        char* base = smc + cur * HALF;
        #pragma unroll
        for (int k2 = 0; k2 < 2; ++k2) {
            bf16x8 af[MT], bfv[NT];
            #pragma unroll
            for (int mt = 0; mt < MT; ++mt) {
                int r = wm + mt * 16 + mrow;
                af[mt] = *(const bf16x8*)(base + r * ROWB
                            + (((k2 * 4 + quad) ^ (r & 7)) << 4));
            }
            #pragma unroll
            for (int nt = 0; nt < NT; ++nt) {
                int r = wn + nt * 16 + mrow;
                bfv[nt] = *(const bf16x8*)(base + BM * ROWB + r * ROWB
                            + (((k2 * 4 + quad) ^ (r & 7)) << 4));
            }
            #pragma unroll
            for (int mt = 0; mt < MT; ++mt)
                #pragma unroll
                for (int nt = 0; nt < NT; ++nt) {
                    if constexpr (MODE == 2)
                        acc[mt][nt] = __builtin_amdgcn_mfma_f32_16x16x32_bf16(
                            bfv[nt], af[mt], acc[mt][nt], 0, 0, 0);
                    else
                        acc[mt][nt] = __builtin_amdgcn_mfma_f32_16x16x32_bf16(
                            af[mt], bfv[nt], acc[mt][nt], 0, 0, 0);
                }
        }

        __syncthreads();
        cur ^= 1;
    }

    if constexpr (MODE == 2) {
        #pragma unroll
        for (int nt = 0; nt < NT; ++nt) {
            #pragma unroll
            for (int r = 0; r < 4; ++r) {
                int ci = bn + wn + nt * 16 + quad * 4 + r;
                #pragma unroll
                for (int mt = 0; mt < MT; ++mt) {
                    int mi = bm + wm + mt * 16 + mrow;
                    float v = acc[mt][nt][r] * alpha;
                    if (hasBias) v += bias[ci];
                    ((__bf16*)Cv)[cBase + (long)ci * ldc + mi] = (__bf16)v;
                }
            }
        }
    } else {
        #pragma unroll
        for (int mt = 0; mt < MT; ++mt) {
            #pragma unroll
            for (int r = 0; r < 4; ++r) {
                int row = bm + wm + mt * 16 + quad * 4 + r;
                #pragma unroll
                for (int nt = 0; nt < NT; ++nt) {
                    int col = bn + wn + nt * 16 + mrow;
                    float v = acc[mt][nt][r] * alpha;
                    if (hasBias) v += bias[col];
                    if constexpr (MODE == 0)
                        ((float*)Cv)[cBase + (long)row * ldc + col] = v;
                    else if constexpr (MODE == 1)
                        ((__bf16*)Cv)[cBase + (long)row * ldc + col] = (__bf16)v;
                    else
                        atomicAdd(&((float*)Cv)[cBase + (long)row * ldc + col], v);
                }
            }
        }
    }
}

// ---------------- prep block: converts/transposes/zeros (R19 wide) ---------
__device__ __forceinline__ void prep_block(const PArgs& a, int bid, void* smv)
{
    int i = 0;
    while (i < a.n && bid >= a.p[i].blocks) { bid -= a.p[i].blocks; ++i; }
    if (i >= a.n) return;
    PD d = a.p[i];
    int t = threadIdx.x;
    if (d.mode == 0) {
        // fp32 -> bf16 transposed, FOUR 32x32 tiles per block
        float (*tile)[33] = (float(*)[33])smv;
        int tC = d.C >> 5, tR = d.R >> 5;
        int tx = t & 31, ty = t >> 5;
        #pragma unroll
        for (int u4 = 0; u4 < 4; ++u4) {
            int tindex = bid * 4 + u4;
            int batch = tindex / (tC * tR), rem = tindex - batch * (tC * tR);
            int tyo = rem / tC, txo = rem - tyo * tC;
            const float* src = d.s + (long)batch * d.R * d.C;
            __bf16* dst = (__bf16*)d.d + (long)batch * d.R * d.C;
            int r0 = tyo * 32, c0 = txo * 32;
            if (u4) __syncthreads();   // LDS reuse fence
            #pragma unroll
            for (int u = 0; u < 4; ++u)
                tile[ty + 8 * u][tx] = src[(long)(r0 + ty + 8 * u) * d.C + c0 + tx];
            __syncthreads();
            #pragma unroll
            for (int u = 0; u < 4; ++u)
                dst[(long)(c0 + ty + 8 * u) * d.R + r0 + tx] = (__bf16)tile[tx][ty + 8 * u];
        }
    } else if (d.mode == 1) {
        // fp32 -> bf16 flat, 16 floats (64B read, 32B write) per thread
        long idx = ((long)bid * 256 + t) * 16;
        long total = (long)d.Bc * d.R * d.C;
        if (idx < total) {
            #pragma unroll
            for (int j = 0; j < 2; ++j) {
                float4 f0 = *(const float4*)(d.s + idx + j * 8);
                float4 f1 = *(const float4*)(d.s + idx + j * 8 + 4);
                bf16x8 v = {(__bf16)f0.x, (__bf16)f0.y, (__bf16)f0.z, (__bf16)f0.w,
                            (__bf16)f1.x, (__bf16)f1.y, (__bf16)f1.z, (__bf16)f1.w};
                *(bf16x8*)((__bf16*)d.d + idx + j * 8) = v;
            }
        }
    } else if (d.mode == 2) {
        long idx = (long)bid * 256 + t;
        long total = (long)d.Bc * d.R * d.C;
        if (idx < total) ((float*)d.d)[idx] = d.s[idx];
    } else {
        // mode 4: zero, 16 floats per thread
        long idx = ((long)bid * 256 + t) * 16;
        long total = (long)d.Bc * d.R * d.C;
        if (idx < total) {
            float4 z{0.f, 0.f, 0.f, 0.f};
            float4* o = (float4*)((float*)d.d + idx);
            o[0] = z; o[1] = z; o[2] = z; o[3] = z;
        }
    }
}

// ---------------- small block: c-vector from S^T (fp32) --------------------
__device__ __forceinline__ void small_block(void* smv,
    const float* __restrict__ STf, const float* __restrict__ bq,
    const __bf16* __restrict__ WoT, const float* __restrict__ boA,
    float* __restrict__ cOut, int ad, int F, long wG, int bid)
{
    int tid = threadIdx.x;
    float* rL  = (float*)smv;
    float* red = (float*)((char*)smv + 4096);
    int g = bid >> 5, slice = bid & 31;
    int nq = F / ad;
    const float* Sg = STf + (long)g * ad * ad;
    for (int f = tid; f < F; f += 256) {
        int q = f / ad, aa = f - q * ad;
        const float* bv = bq + (long)(g * nq + q) * ad;
        const float* Sa = Sg + (long)aa * ad;
        float s = 0.f;
        for (int c = 0; c < ad; c += 4) {
            float4 b4 = *(const float4*)(bv + c);
            float4 s4 = *(const float4*)(Sa + c);
            s += b4.x * s4.x + b4.y * s4.y + b4.z * s4.z + b4.w * s4.w;
        }
        rL[f] = s;
    }
    __syncthreads();
    int dl = tid & 15, fs = tid >> 4;
    int d = slice * 16 + dl;
    int fchunk = F >> 4;
    const __bf16* wrow = WoT + (long)g * wG + (long)d * F;
    float s = 0.f;
    for (int f0 = fs * fchunk; f0 < (fs + 1) * fchunk; f0 += 8) {
        bf16x8 w = *(const bf16x8*)(wrow + f0);
        s += rL[f0]     * (float)w[0] + rL[f0 + 1] * (float)w[1]
           + rL[f0 + 2] * (float)w[2] + rL[f0 + 3] * (float)w[3]
           + rL[f0 + 4] * (float)w[4] + rL[f0 + 5] * (float)w[5]
           + rL[f0 + 6] * (float)w[6] + rL[f0 + 7] * (float)w[7];
    }
    red[tid] = s;
    __syncthreads();
    if (fs == 0) {
        float tsum = s;
        #pragma unroll
        for (int u = 1; u < 16; ++u) tsum += red[u * 16 + dl];
        cOut[(long)g * 512 + d] = boA[(long)g * 512 + d] + tsum;
    }
}

// outp[g][d] = bias[d] + sum_f v[g][f] * WT[d][f]   (F=512)
__device__ __forceinline__ void vecmat_block(void* smv,
    const float* __restrict__ v, const __bf16* __restrict__ WT,
    const float* __restrict__ bias, float* __restrict__ outp, int g, int slice)
{
    float* red2 = (float*)smv;
    int tid = threadIdx.x;
    int dl = tid & 15, fs = tid >> 4;
    int d = slice * 16 + dl;
    const float* vg = v + (long)g * 512;
    const __bf16* wrow = WT + (long)d * 512;
    float s = 0.f;
    for (int f0 = fs * 32; f0 < (fs + 1) * 32; f0 += 8) {
        bf16x8 w = *(const bf16x8*)(wrow + f0);
        s += vg[f0]     * (float)w[0] + vg[f0 + 1] * (float)w[1]
           + vg[f0 + 2] * (float)w[2] + vg[f0 + 3] * (float)w[3]
           + vg[f0 + 4] * (float)w[4] + vg[f0 + 5] * (float)w[5]
           + vg[f0 + 6] * (float)w[6] + vg[f0 + 7] * (float)w[7];
    }
    red2[tid] = s;
    __syncthreads();
    if (fs == 0) {
        float tsum = s;
        #pragma unroll
        for (int u = 1; u < 16; ++u) tsum += red2[u * 16 + dl];
        outp[(long)g * 512 + d] = bias[d] + tsum;
    }
}

// ---------------- stages (compile-time dispatch) ----------------------------
template<int S>
__device__ __forceinline__ void run_stage(const MA& a, int vb, void* sm)
{
    const float isa1 = 0.08838834764831845f;  // 1/sqrt(128)
    if constexpr (S == 0) {
        prep_block(a.pa, vb, sm);
    } else if constexpr (S == 1) {   // KV1 (1024) | Wo2p (512) | bo2p (256)
        if (vb < 1024)
            gemm_block<64,64,2>(sm, a.xb, a.Wk1t, a.kvb1, a.Ktb,
                512, 512, 512, 2048, 1, 1,
                0L, 0L, 65536L, 0L, 262144L, 0L, 128L, 0L, 1, 1.0f,
                vb & 1, (vb >> 1) & 31, vb >> 6);
        else if (vb < 1536) {
            int v = vb - 1024;
            gemm_block<64,64,2>(sm, a.Wo2b, a.Wot, nullptr, a.Wo2pT,
                512, 512, 512, 512, 1, 1,
                262144L, 0L, 0L, 0L, 262144L, 0L, 0L, 0L, 0, 1.0f,
                v & 7, (v >> 3) & 7, v >> 6);
        } else {
            int v = vb - 1536;
            vecmat_block(sm, a.bo2, a.Wot, a.bo, a.bo2p, v & 7, v >> 3);
        }
    } else if constexpr (S == 2) {   // S1^T split-K x32 atomic (1024)
        gemm_block<64,64,3>(sm, a.Vtb, a.Ktb, nullptr, a.STf1,
            2048, 2048, 2048, 128, 1, 32,
            262144L, 0L, 262144L, 0L, 16384L, 0L, 0L, 0L, 0, isa1,
            vb & 1, (vb >> 1) & 1, vb >> 2);
    } else if constexpr (S == 3) {   // c1 (256, FIRST) | T1 ss_gemm (512)
        if (vb < 256)
            small_block(sm, a.STf1, a.bq1, a.Wo1t, a.bo1, a.c1,
                        128, 1024, 524288L, vb);
        else
            ss_gemm<64,128,128>(sm, a.Wq1b, a.STf1, a.T1b,
                                524288L, 16384L, 524288L, 1024, 128, vb - 256);
    } else if constexpr (S == 4) {   // M1^T (512)
        gemm_block<64,64,2>(sm, a.T1b, a.Wo1t, nullptr, a.M1t,
            1024, 1024, 1024, 512, 1, 1,
            524288L, 0L, 524288L, 0L, 262144L, 0L, 0L, 0L, 0, 1.0f,
            vb & 7, (vb >> 3) & 7, vb >> 6);
    } else if constexpr (S == 5) {   // o1 = x.M1 + c1 (512, 128^2)
        gemm_block<128,128,1>(sm, a.xb, a.M1t, a.c1, a.o1b,
            512, 512, 512, 512, 1, 1,
            0L, 0L, 262144L, 0L, 1048576L, 0L, 512L, 0L, 1, 1.0f,
            vb & 3, (vb >> 2) & 15, vb >> 6);
    } else if constexpr (S == 6) {   // KV2 fused (512)
        gemm_block<64,64,2>(sm, a.o1b, a.Wk2t, a.kvb2, a.K2tb,
            512, 512, 512, 2048, 8, 1,
            0L, 1048576L, 262144L, 32768L, 1048576L, 131072L, 512L, 64L,
            1, 1.0f, 0, vb & 31, vb >> 5);
    } else if constexpr (S == 7) {   // S2^T split-K x32 atomic (256)
        gemm_block<64,64,3>(sm, a.V2tb, a.K2tb, nullptr, a.STf2,
            2048, 2048, 2048, 64, 1, 32,
            131072L, 0L, 131072L, 0L, 4096L, 0L, 0L, 0L, 0, 0.125f,
            0, 0, vb);
    } else if constexpr (S == 8) {   // c2p (256, FIRST) | T2 ss_gemm (512)
        if (vb < 256)
            small_block(sm, a.STf2, a.bq2, a.Wo2pT, a.bo2p, a.c2p,
                        64, 512, 262144L, vb);
        else
            ss_gemm<64,64,64>(sm, a.Wq2b, a.STf2, a.T2b,
                              262144L, 4096L, 262144L, 512, 64, vb - 256);
    } else if constexpr (S == 9) {   // M2p^T = (T2.Wo2p)^T (512)
        gemm_block<64,64,2>(sm, a.T2b, a.Wo2pT, nullptr, a.M2pt,
            512, 512, 512, 512, 1, 1,
            262144L, 0L, 262144L, 0L, 262144L, 0L, 0L, 0L, 0, 1.0f,
            vb & 7, (vb >> 3) & 7, vb >> 6);
    } else {                         // 10: out = o1.M2p + c2p (512, 128^2)
        gemm_block<128,128,0>(sm, a.o1b, a.M2pt, a.c2p, a.out,
            512, 512, 512, 512, 1, 1,
            1048576L, 0L, 262144L, 0L, 1048576L, 0L, 512L, 0L, 1, 1.0f,
            vb & 3, (vb >> 2) & 15, vb >> 6);
    }
}

#define STAGE_KERNEL(NAME, S, SMEM, MINW)                                    \
__global__ __launch_bounds__(256, MINW) void NAME(MA a)                      \
{                                                                            \
    __shared__ __align__(16) unsigned char smem[SMEM];                       \
    run_stage<S>(a, blockIdx.x, smem);                                       \
}

STAGE_KERNEL(ksg0_prep,    0, 16384, 4)
STAGE_KERNEL(ksg1_kv1wo2p, 1, 32768, 4)
STAGE_KERNEL(ksg2_s1t,     2, 32768, 4)
STAGE_KERNEL(ksg3_t1c1,    3, 49152, 4)   // ss_gemm A 16K + B 32K
STAGE_KERNEL(ksg4_m1t,     4, 32768, 4)
STAGE_KERNEL(ksg5_o1,      5, 65536, 2)   // 128^2, BK=64 dbuf
STAGE_KERNEL(ksg6_kv2,     6, 32768, 4)
STAGE_KERNEL(ksg7_s2t,     7, 32768, 4)
STAGE_KERNEL(ksg8_t2c2p,   8, 16384, 4)
STAGE_KERNEL(ksg9_m2pt,    9, 32768, 4)
STAGE_KERNEL(ksg10_out,   10, 65536, 2)

extern "C" void kernel_launch(void* const* d_in, const int* in_sizes, int n_in,
                              void* d_out, int out_size, void* d_ws, size_t ws_size,
                              hipStream_t stream)
{
    MA ma;
    ma.x   = (const float*)d_in[0];
    const float* Wq1 = (const float*)d_in[1];  ma.bq1 = (const float*)d_in[2];
    const float* Wk1 = (const float*)d_in[3];  const float* bk1 = (const float*)d_in[4];
    const float* Wv1 = (const float*)d_in[5];  const float* bv1 = (const float*)d_in[6];
    const float* Wo1 = (const float*)d_in[7];  ma.bo1 = (const float*)d_in[8];
    const float* Wq2 = (const float*)d_in[9];  ma.bq2 = (const float*)d_in[10];
    const float* Wk2 = (const float*)d_in[11]; const float* bk2 = (const float*)d_in[12];
    const float* Wv2 = (const float*)d_in[13]; const float* bv2 = (const float*)d_in[14];
    const float* Wo2 = (const float*)d_in[15]; ma.bo2 = (const float*)d_in[16];
    const float* Wo  = (const float*)d_in[17]; ma.bo  = (const float*)d_in[18];
    ma.out = (float*)d_out;
    (void)in_sizes; (void)n_in; (void)out_size; (void)ws_size;

    __bf16* wb = (__bf16*)d_ws;
    long o = 0;
    ma.xb    = wb + o; o += 1048576;
    ma.Wk1t  = wb + o; o += 524288;
    ma.Wv1t  = wb + o; o += 524288;
    ma.Wq1b  = wb + o; o += 4194304;
    ma.Wo1t  = wb + o; o += 4194304;
    ma.Wk2t  = wb + o; o += 262144;
    ma.Wv2t  = wb + o; o += 262144;
    ma.Wq2b  = wb + o; o += 2097152;
    ma.Wo2b  = wb + o; o += 2097152;   // Wo2 bf16 flat [g][512f][512d]
    ma.Wot   = wb + o; o += 262144;    // Wo^T [512e][512d]
    ma.Ktb   = wb + o; o += 2097152;   // K1^T [g][128][2048]
    ma.Vtb   = wb + o; o += 2097152;
    ma.T1b   = wb + o; o += 4194304;
    ma.M1t   = wb + o; o += 2097152;
    ma.o1b   = wb + o; o += 8388608;
    ma.K2tb  = ma.Ktb;                 // alias: K2^T [g][64][2048]
    ma.V2tb  = ma.Ktb + 1048576;       // alias: V2^T
    ma.T2b   = wb + o; o += 2097152;
    ma.Wo2pT = wb + o; o += 2097152;   // (Wo2@Wo)^T [g][512e][512f]
    ma.M2pt  = wb + o; o += 2097152;
    float* wf = (float*)(wb + o);
    long p = 0;
    ma.STf1 = wf + p; p += 131072;
    ma.STf2 = wf + p; p += 32768;
    ma.kvb1 = wf + p; p += 2048;
    ma.kvb2 = wf + p; p += 1024;
    ma.c1   = wf + p; p += 4096;
    ma.c2p  = wf + p; p += 4096;
    ma.bo2p = wf + p; p += 4096;

    int nd = 0, totB = 0;
    auto add = [&](const float* s, void* d, int R, int C, int Bc, int mode) {
        int blocks;
        long total = (long)Bc * R * C;
        if (mode == 0) blocks = Bc * (R >> 5) * (C >> 5) / 4;      // 4 tiles/blk
        else if (mode == 1) blocks = (int)(total / 4096);          // 16 f/thread
        else if (mode == 4) blocks = (int)((total + 4095) / 4096); // 16 f/thread
        else blocks = (int)((total + 255) / 256);
        ma.pa.p[nd] = PD{s, d, R, C, Bc, mode, blocks};
        ++nd; totB += blocks;
    };
    add(ma.x, ma.xb,   2048, 512, 1, 1);
    add(Wq1,  ma.Wq1b, 512, 128, 64, 1);
    add(Wq2,  ma.Wq2b, 512, 64, 64, 1);
    add(Wo2,  ma.Wo2b, 512, 512, 8, 1);
    add(Wk1,  ma.Wk1t, 512, 128, 8, 0);
    add(Wv1,  ma.Wv1t, 512, 128, 8, 0);
    add(Wo1,  ma.Wo1t, 1024, 512, 8, 0);
    add(Wk2,  ma.Wk2t, 512, 64, 8, 0);
    add(Wv2,  ma.Wv2t, 512, 64, 8, 0);
    add(Wo,   ma.Wot,  512, 512, 1, 0);
    add(bk1,  ma.kvb1,        1, 1024, 1, 2);
    add(bv1,  ma.kvb1 + 1024, 1, 1024, 1, 2);
    add(bk2,  ma.kvb2,        1, 512, 1, 2);
    add(bv2,  ma.kvb2 + 512,  1, 512, 1, 2);
    add(nullptr, ma.STf1, 1, 131072, 1, 4);
    add(nullptr, ma.STf2, 1, 32768, 1, 4);
    ma.pa.n = nd;
    ma.prepTot = totB;

    ksg0_prep   <<<dim3(ma.prepTot), dim3(256), 0, stream>>>(ma);
    ksg1_kv1wo2p<<<dim3(1792), dim3(256), 0, stream>>>(ma);
    ksg2_s1t    <<<dim3(1024), dim3(256), 0, stream>>>(ma);
    ksg3_t1c1   <<<dim3(768),  dim3(256), 0, stream>>>(ma);
    ksg4_m1t    <<<dim3(512),  dim3(256), 0, stream>>>(ma);
    ksg5_o1     <<<dim3(512),  dim3(256), 0, stream>>>(ma);
    ksg6_kv2    <<<dim3(512),  dim3(256), 0, stream>>>(ma);
    ksg7_s2t    <<<dim3(256),  dim3(256), 0, stream>>>(ma);
    ksg8_t2c2p  <<<dim3(768),  dim3(256), 0, stream>>>(ma);
    ksg9_m2pt   <<<dim3(512),  dim3(256), 0, stream>>>(ma);
    ksg10_out   <<<dim3(512),  dim3(256), 0, stream>>>(ma);
}

// Round 10
// 264.377 us; speedup vs baseline: 1.0351x; 1.0351x over previous
//
#include <hip/hip_runtime.h>

// N=2048, D=512, A=64, NQ=8, G1=G2=8, A1=128.
// Algebra (no softmax): ctx = q (K^T V)/sqrt(a) => per-group fold:
//   S[g]=(xWk+bk)^T(xWv+bv)/sqrt(a); M[g]=sum_q Wq S Wo_q; o[g]=x M[g]+c[g];
//   tier2 same; Wo2p[g]=Wo2[g]@Wo precomputed => M2p = T2@Wo2p,
//   c2p = r2@Wo2p + (bo2@Wo + bo).
// R19 post-mortem: +14us REGRESSION. Attribution: ksplit 8->32 on stage 2
//   = 32 atomicAdds/element vs 8 = +12MB extra L2 RMW traffic on a 512KB
//   hot region (+10-14us, matches); stage 7 similar. Prep vectorization
//   (same bytes, wider lanes) is mechanistically neutral-positive.
// R20: surgical revert — stage 2 ksplit back to 8 (grid 256), stage 7 back
//   to 16 (grid 128) = R18's proven config; KEEP R19's wide prep.
// Carried: BK=64 XOR-swizzled 2-phase gemm_block (R15), ss_gemm (R13),
//   mode-2 swapped-operand transposed store (R14), small-first (R18).

typedef __bf16 bf16x8 __attribute__((ext_vector_type(8)));
typedef float  f32x4  __attribute__((ext_vector_type(4)));

struct PD { const float* s; void* d; int R, C, Bc, mode, blocks; };
struct PArgs { PD p[20]; int n; };

struct MA {
    const float *x,*bq1,*bo1,*bq2,*bo2,*bo;
    float* out;
    __bf16 *xb,*Wk1t,*Wv1t,*Wq1b,*Wo1t,*Wk2t,*Wv2t,*Wq2b,*Wo2b,*Wot;
    __bf16 *Ktb,*Vtb,*T1b,*M1t,*o1b,*K2tb,*V2tb,*T2b,*Wo2pT,*M2pt;
    float *STf1,*STf2,*kvb1,*kvb2,*c1,*c2p,*bo2p;
    PArgs pa;
    int prepTot;
};

// ---------------- single-shot-K GEMM (K fits LDS; one barrier) -------------
template<int BM, int BN, int KK>
__device__ __forceinline__ void ss_gemm(void* smv,
    const __bf16* __restrict__ A, const float* __restrict__ Bf,
    __bf16* __restrict__ C, long aG, long bG, long cG, int cD, int cQ, int vb)
{
    constexpr int MT = BM / 32, NT = BN / 32, KS = KK / 32;
    constexpr int ACH = (KK * 2) / 16;
    constexpr int ABYTES = BM * KK * 2;
    constexpr int AITER = ABYTES / 16 / 256;
    constexpr int ROWB = KK * 2;
    constexpr int F4PT = (BN * KK) / 4 / 256;
    constexpr int TPR  = (KK / 4) / F4PT;

    char* smc = (char*)smv;
    int g = vb >> 6, rb = vb & 63;
    A  += g * aG + (long)rb * BM * KK;
    Bf += g * bG;
    C  += g * cG;

    int tid = threadIdx.x, wave = tid >> 6, lane = tid & 63;
    int mrow = lane & 15, quad = lane >> 4;

    #pragma unroll
    for (int i = 0; i < AITER; ++i) {
        int c = tid + i * 256;
        int row = c / ACH, cp = c % ACH;
        int cg = cp ^ (row & 7);
        __builtin_amdgcn_global_load_lds(
            (const __attribute__((address_space(1))) void*)(A + (long)row * KK + cg * 8),
            (__attribute__((address_space(3))) void*)(smc + c * 16),
            16, 0, 0);
    }
    {
        int brow = tid / TPR, bseg = tid % TPR;
        const float4* bsrc = (const float4*)(Bf + (long)brow * KK + bseg * (KK / TPR));
        int cbase = (bseg * (KK / TPR)) >> 3;
        int bx7 = brow & 7;
        char* bls = smc + ABYTES + (long)brow * ROWB;
        #pragma unroll
        for (int j = 0; j < F4PT / 2; ++j) {
            float4 f0 = bsrc[2 * j], f1 = bsrc[2 * j + 1];
            bf16x8 v = {(__bf16)f0.x, (__bf16)f0.y, (__bf16)f0.z, (__bf16)f0.w,
                        (__bf16)f1.x, (__bf16)f1.y, (__bf16)f1.z, (__bf16)f1.w};
            *(bf16x8*)(bls + (((cbase + j) ^ bx7) << 4)) = v;
        }
    }
    __syncthreads();

    int wm = (wave >> 1) * (BM / 2), wn = (wave & 1) * (BN / 2);
    f32x4 acc[MT][NT];
    #pragma unroll
    for (int i = 0; i < MT; ++i)
        #pragma unroll
        for (int j = 0; j < NT; ++j)
            acc[i][j] = f32x4{0.f, 0.f, 0.f, 0.f};

    #pragma unroll
    for (int ks = 0; ks < KS; ++ks) {
        bf16x8 af[MT], bv[NT];
        #pragma unroll
        for (int mt = 0; mt < MT; ++mt) {
            int r = wm + mt * 16 + mrow;
            af[mt] = *(const bf16x8*)(smc + (long)r * ROWB
                        + (((ks * 4 + quad) ^ (r & 7)) << 4));
        }
        #pragma unroll
        for (int nt = 0; nt < NT; ++nt) {
            int r = wn + nt * 16 + mrow;
            bv[nt] = *(const bf16x8*)(smc + ABYTES + (long)r * ROWB
                        + (((ks * 4 + quad) ^ (r & 7)) << 4));
        }
        #pragma unroll
        for (int mt = 0; mt < MT; ++mt)
            #pragma unroll
            for (int nt = 0; nt < NT; ++nt)
                acc[mt][nt] = __builtin_amdgcn_mfma_f32_16x16x32_bf16(
                    af[mt], bv[nt], acc[mt][nt], 0, 0, 0);
    }

    #pragma unroll
    for (int mt = 0; mt < MT; ++mt) {
        #pragma unroll
        for (int r4 = 0; r4 < 4; ++r4) {
            int rl = wm + mt * 16 + quad * 4 + r4;
            int ra = rb * BM + rl;
            int q = ra >> 9, d = ra & 511;
            #pragma unroll
            for (int nt = 0; nt < NT; ++nt) {
                int col = wn + nt * 16 + mrow;
                C[(long)d * cD + q * cQ + col] = (__bf16)acc[mt][nt][r4];
            }
        }
    }
}

// ---------------- bf16 MFMA GEMM block, C = alpha*(A.B^T) (+bias) ----------
// MODE: 0=f32, 1=bf16, 2=bf16 transposed (swapped MFMA operands), 3=f32 atomic.
// BK=64 2-phase XOR-swizzled pipeline (R15).
template<int BM, int BN, int MODE>
__device__ __forceinline__ void gemm_block(void* smv,
    const __bf16* __restrict__ A, const __bf16* __restrict__ B,
    const float* __restrict__ bias, void* __restrict__ Cv,
    int K, int lda, int ldb, int ldc, int divq, int ksplit,
    long aOut, long aIn, long bOut, long bIn, long cOut, long cIn,
    long biasOut, long biasIn, int hasBias, float alpha,
    int bx, int by, int bz)
{
    constexpr int MT = BM / 32, NT = BN / 32;
    constexpr int ROWB = 128;
    constexpr int HALF = (BM + BN) * ROWB;
    constexpr int AOPS = BM * 8 / 256;
    constexpr int BOPS = BN * 8 / 256;

    char* smc = (char*)smv;

    int b  = bz / ksplit, ks = bz - b * ksplit;
    int go = b / divq,  gi = b - go * divq;
    A += go * aOut + gi * aIn;
    B += go * bOut + gi * bIn;
    long cBase = go * cOut + gi * cIn;
    if (hasBias) bias += go * biasOut + gi * biasIn;

    int kChunk = K / ksplit;
    int k0 = ks * kChunk;
    int nT = kChunk / 64;

    int bm = by * BM, bn = bx * BN;
    int tid = threadIdx.x, wave = tid >> 6, lane = tid & 63;
    int wm = (wave >> 1) * (BM / 2), wn = (wave & 1) * (BN / 2);
    int mrow = lane & 15, quad = lane >> 4;

    f32x4 acc[MT][NT];
    #pragma unroll
    for (int i = 0; i < MT; ++i)
        #pragma unroll
        for (int j = 0; j < NT; ++j)
            acc[i][j] = f32x4{0.f, 0.f, 0.f, 0.f};

    auto issueAB = [&](int buf, int kk) {
        char* base = smc + buf * HALF;
        #pragma unroll
        for (int t = 0; t < AOPS; ++t) {
            int c = tid + t * 256;
            int row = c >> 3, cp = c & 7;
            int cg = cp ^ (row & 7);
            __builtin_amdgcn_global_load_lds(
                (const __attribute__((address_space(1))) void*)
                    (A + (long)(bm + row) * lda + kk + cg * 8),
                (__attribute__((address_space(3))) void*)(base + c * 16),
                16, 0, 0);
        }
        char* bbase = base + BM * ROWB;
        #pragma unroll
        for (int t = 0; t < BOPS; ++t) {
            int c = tid + t * 256;
            int row = c >> 3, cp = c & 7;
            int cg = cp ^ (row & 7);
            __builtin_amdgcn_global_load_lds(
                (const __attribute__((address_space(1))) void*)
                    (B + (long)(bn + row) * ldb + kk + cg * 8),
                (__attribute__((address_space(3))) void*)(bbase + c * 16),
                16, 0, 0);
        }
    };

    issueAB(0, k0);
    __syncthreads();

    int cur = 0;
    for (int t = 0; t < nT; ++t) {
        if (t + 1 < nT) issueAB(cur ^ 1, k0 + (t + 1) * 64);

        char* base = smc + cur * HALF;
        #pragma unroll
        for (int k2 = 0; k2 < 2; ++k2) {
            bf16x8 af[MT], bfv[NT];
            #pragma unroll
            for (int mt = 0; mt < MT; ++mt) {
                int r = wm + mt * 16 + mrow;
                af[mt] = *(const bf16x8*)(base + r * ROWB
                            + (((k2 * 4 + quad) ^ (r & 7)) << 4));
            }
            #pragma unroll
            for (int nt = 0; nt < NT; ++nt) {
                int r = wn + nt * 16 + mrow;
                bfv[nt] = *(const bf16x8*)(base + BM * ROWB + r * ROWB
                            + (((k2 * 4 + quad) ^ (r & 7)) << 4));
            }
            #pragma unroll
            for (int mt = 0; mt < MT; ++mt)
                #pragma unroll
                for (int nt = 0; nt < NT; ++nt) {
                    if constexpr (MODE == 2)
                        acc[mt][nt] = __builtin_amdgcn_mfma_f32_16x16x32_bf16(
                            bfv[nt], af[mt], acc[mt][nt], 0, 0, 0);
                    else
                        acc[mt][nt] = __builtin_amdgcn_mfma_f32_16x16x32_bf16(
                            af[mt], bfv[nt], acc[mt][nt], 0, 0, 0);
                }
        }

        __syncthreads();
        cur ^= 1;
    }

    if constexpr (MODE == 2) {
        #pragma unroll
        for (int nt = 0; nt < NT; ++nt) {
            #pragma unroll
            for (int r = 0; r < 4; ++r) {
                int ci = bn + wn + nt * 16 + quad * 4 + r;
                #pragma unroll
                for (int mt = 0; mt < MT; ++mt) {
                    int mi = bm + wm + mt * 16 + mrow;
                    float v = acc[mt][nt][r] * alpha;
                    if (hasBias) v += bias[ci];
                    ((__bf16*)Cv)[cBase + (long)ci * ldc + mi] = (__bf16)v;
                }
            }
        }
    } else {
        #pragma unroll
        for (int mt = 0; mt < MT; ++mt) {
            #pragma unroll
            for (int r = 0; r < 4; ++r) {
                int row = bm + wm + mt * 16 + quad * 4 + r;
                #pragma unroll
                for (int nt = 0; nt < NT; ++nt) {
                    int col = bn + wn + nt * 16 + mrow;
                    float v = acc[mt][nt][r] * alpha;
                    if (hasBias) v += bias[col];
                    if constexpr (MODE == 0)
                        ((float*)Cv)[cBase + (long)row * ldc + col] = v;
                    else if constexpr (MODE == 1)
                        ((__bf16*)Cv)[cBase + (long)row * ldc + col] = (__bf16)v;
                    else
                        atomicAdd(&((float*)Cv)[cBase + (long)row * ldc + col], v);
                }
            }
        }
    }
}

// ---------------- prep block: converts/transposes/zeros (R19 wide) ---------
__device__ __forceinline__ void prep_block(const PArgs& a, int bid, void* smv)
{
    int i = 0;
    while (i < a.n && bid >= a.p[i].blocks) { bid -= a.p[i].blocks; ++i; }
    if (i >= a.n) return;
    PD d = a.p[i];
    int t = threadIdx.x;
    if (d.mode == 0) {
        // fp32 -> bf16 transposed, FOUR 32x32 tiles per block
        float (*tile)[33] = (float(*)[33])smv;
        int tC = d.C >> 5, tR = d.R >> 5;
        int tx = t & 31, ty = t >> 5;
        #pragma unroll
        for (int u4 = 0; u4 < 4; ++u4) {
            int tindex = bid * 4 + u4;
            int batch = tindex / (tC * tR), rem = tindex - batch * (tC * tR);
            int tyo = rem / tC, txo = rem - tyo * tC;
            const float* src = d.s + (long)batch * d.R * d.C;
            __bf16* dst = (__bf16*)d.d + (long)batch * d.R * d.C;
            int r0 = tyo * 32, c0 = txo * 32;
            if (u4) __syncthreads();   // LDS reuse fence
            #pragma unroll
            for (int u = 0; u < 4; ++u)
                tile[ty + 8 * u][tx] = src[(long)(r0 + ty + 8 * u) * d.C + c0 + tx];
            __syncthreads();
            #pragma unroll
            for (int u = 0; u < 4; ++u)
                dst[(long)(c0 + ty + 8 * u) * d.R + r0 + tx] = (__bf16)tile[tx][ty + 8 * u];
        }
    } else if (d.mode == 1) {
        // fp32 -> bf16 flat, 16 floats (64B read, 32B write) per thread
        long idx = ((long)bid * 256 + t) * 16;
        long total = (long)d.Bc * d.R * d.C;
        if (idx < total) {
            #pragma unroll
            for (int j = 0; j < 2; ++j) {
                float4 f0 = *(const float4*)(d.s + idx + j * 8);
                float4 f1 = *(const float4*)(d.s + idx + j * 8 + 4);
                bf16x8 v = {(__bf16)f0.x, (__bf16)f0.y, (__bf16)f0.z, (__bf16)f0.w,
                            (__bf16)f1.x, (__bf16)f1.y, (__bf16)f1.z, (__bf16)f1.w};
                *(bf16x8*)((__bf16*)d.d + idx + j * 8) = v;
            }
        }
    } else if (d.mode == 2) {
        long idx = (long)bid * 256 + t;
        long total = (long)d.Bc * d.R * d.C;
        if (idx < total) ((float*)d.d)[idx] = d.s[idx];
    } else {
        // mode 4: zero, 16 floats per thread
        long idx = ((long)bid * 256 + t) * 16;
        long total = (long)d.Bc * d.R * d.C;
        if (idx < total) {
            float4 z{0.f, 0.f, 0.f, 0.f};
            float4* o = (float4*)((float*)d.d + idx);
            o[0] = z; o[1] = z; o[2] = z; o[3] = z;
        }
    }
}

// ---------------- small block: c-vector from S^T (fp32) --------------------
__device__ __forceinline__ void small_block(void* smv,
    const float* __restrict__ STf, const float* __restrict__ bq,
    const __bf16* __restrict__ WoT, const float* __restrict__ boA,
    float* __restrict__ cOut, int ad, int F, long wG, int bid)
{
    int tid = threadIdx.x;
    float* rL  = (float*)smv;
    float* red = (float*)((char*)smv + 4096);
    int g = bid >> 5, slice = bid & 31;
    int nq = F / ad;
    const float* Sg = STf + (long)g * ad * ad;
    for (int f = tid; f < F; f += 256) {
        int q = f / ad, aa = f - q * ad;
        const float* bv = bq + (long)(g * nq + q) * ad;
        const float* Sa = Sg + (long)aa * ad;
        float s = 0.f;
        for (int c = 0; c < ad; c += 4) {
            float4 b4 = *(const float4*)(bv + c);
            float4 s4 = *(const float4*)(Sa + c);
            s += b4.x * s4.x + b4.y * s4.y + b4.z * s4.z + b4.w * s4.w;
        }
        rL[f] = s;
    }
    __syncthreads();
    int dl = tid & 15, fs = tid >> 4;
    int d = slice * 16 + dl;
    int fchunk = F >> 4;
    const __bf16* wrow = WoT + (long)g * wG + (long)d * F;
    float s = 0.f;
    for (int f0 = fs * fchunk; f0 < (fs + 1) * fchunk; f0 += 8) {
        bf16x8 w = *(const bf16x8*)(wrow + f0);
        s += rL[f0]     * (float)w[0] + rL[f0 + 1] * (float)w[1]
           + rL[f0 + 2] * (float)w[2] + rL[f0 + 3] * (float)w[3]
           + rL[f0 + 4] * (float)w[4] + rL[f0 + 5] * (float)w[5]
           + rL[f0 + 6] * (float)w[6] + rL[f0 + 7] * (float)w[7];
    }
    red[tid] = s;
    __syncthreads();
    if (fs == 0) {
        float tsum = s;
        #pragma unroll
        for (int u = 1; u < 16; ++u) tsum += red[u * 16 + dl];
        cOut[(long)g * 512 + d] = boA[(long)g * 512 + d] + tsum;
    }
}

// outp[g][d] = bias[d] + sum_f v[g][f] * WT[d][f]   (F=512)
__device__ __forceinline__ void vecmat_block(void* smv,
    const float* __restrict__ v, const __bf16* __restrict__ WT,
    const float* __restrict__ bias, float* __restrict__ outp, int g, int slice)
{
    float* red2 = (float*)smv;
    int tid = threadIdx.x;
    int dl = tid & 15, fs = tid >> 4;
    int d = slice * 16 + dl;
    const float* vg = v + (long)g * 512;
    const __bf16* wrow = WT + (long)d * 512;
    float s = 0.f;
    for (int f0 = fs * 32; f0 < (fs + 1) * 32; f0 += 8) {
        bf16x8 w = *(const bf16x8*)(wrow + f0);
        s += vg[f0]     * (float)w[0] + vg[f0 + 1] * (float)w[1]
           + vg[f0 + 2] * (float)w[2] + vg[f0 + 3] * (float)w[3]
           + vg[f0 + 4] * (float)w[4] + vg[f0 + 5] * (float)w[5]
           + vg[f0 + 6] * (float)w[6] + vg[f0 + 7] * (float)w[7];
    }
    red2[tid] = s;
    __syncthreads();
    if (fs == 0) {
        float tsum = s;
        #pragma unroll
        for (int u = 1; u < 16; ++u) tsum += red2[u * 16 + dl];
        outp[(long)g * 512 + d] = bias[d] + tsum;
    }
}

// ---------------- stages (compile-time dispatch) ----------------------------
template<int S>
__device__ __forceinline__ void run_stage(const MA& a, int vb, void* sm)
{
    const float isa1 = 0.08838834764831845f;  // 1/sqrt(128)
    if constexpr (S == 0) {
        prep_block(a.pa, vb, sm);
    } else if constexpr (S == 1) {   // KV1 (1024) | Wo2p (512) | bo2p (256)
        if (vb < 1024)
            gemm_block<64,64,2>(sm, a.xb, a.Wk1t, a.kvb1, a.Ktb,
                512, 512, 512, 2048, 1, 1,
                0L, 0L, 65536L, 0L, 262144L, 0L, 128L, 0L, 1, 1.0f,
                vb & 1, (vb >> 1) & 31, vb >> 6);
        else if (vb < 1536) {
            int v = vb - 1024;
            gemm_block<64,64,2>(sm, a.Wo2b, a.Wot, nullptr, a.Wo2pT,
                512, 512, 512, 512, 1, 1,
                262144L, 0L, 0L, 0L, 262144L, 0L, 0L, 0L, 0, 1.0f,
                v & 7, (v >> 3) & 7, v >> 6);
        } else {
            int v = vb - 1536;
            vecmat_block(sm, a.bo2, a.Wot, a.bo, a.bo2p, v & 7, v >> 3);
        }
    } else if constexpr (S == 2) {   // S1^T split-K x8 atomic (256)
        gemm_block<64,64,3>(sm, a.Vtb, a.Ktb, nullptr, a.STf1,
            2048, 2048, 2048, 128, 1, 8,
            262144L, 0L, 262144L, 0L, 16384L, 0L, 0L, 0L, 0, isa1,
            vb & 1, (vb >> 1) & 1, vb >> 2);
    } else if constexpr (S == 3) {   // c1 (256, FIRST) | T1 ss_gemm (512)
        if (vb < 256)
            small_block(sm, a.STf1, a.bq1, a.Wo1t, a.bo1, a.c1,
                        128, 1024, 524288L, vb);
        else
            ss_gemm<64,128,128>(sm, a.Wq1b, a.STf1, a.T1b,
                                524288L, 16384L, 524288L, 1024, 128, vb - 256);
    } else if constexpr (S == 4) {   // M1^T (512)
        gemm_block<64,64,2>(sm, a.T1b, a.Wo1t, nullptr, a.M1t,
            1024, 1024, 1024, 512, 1, 1,
            524288L, 0L, 524288L, 0L, 262144L, 0L, 0L, 0L, 0, 1.0f,
            vb & 7, (vb >> 3) & 7, vb >> 6);
    } else if constexpr (S == 5) {   // o1 = x.M1 + c1 (512, 128^2)
        gemm_block<128,128,1>(sm, a.xb, a.M1t, a.c1, a.o1b,
            512, 512, 512, 512, 1, 1,
            0L, 0L, 262144L, 0L, 1048576L, 0L, 512L, 0L, 1, 1.0f,
            vb & 3, (vb >> 2) & 15, vb >> 6);
    } else if constexpr (S == 6) {   // KV2 fused (512)
        gemm_block<64,64,2>(sm, a.o1b, a.Wk2t, a.kvb2, a.K2tb,
            512, 512, 512, 2048, 8, 1,
            0L, 1048576L, 262144L, 32768L, 1048576L, 131072L, 512L, 64L,
            1, 1.0f, 0, vb & 31, vb >> 5);
    } else if constexpr (S == 7) {   // S2^T split-K x16 atomic (128)
        gemm_block<64,64,3>(sm, a.V2tb, a.K2tb, nullptr, a.STf2,
            2048, 2048, 2048, 64, 1, 16,
            131072L, 0L, 131072L, 0L, 4096L, 0L, 0L, 0L, 0, 0.125f,
            0, 0, vb);
    } else if constexpr (S == 8) {   // c2p (256, FIRST) | T2 ss_gemm (512)
        if (vb < 256)
            small_block(sm, a.STf2, a.bq2, a.Wo2pT, a.bo2p, a.c2p,
                        64, 512, 262144L, vb);
        else
            ss_gemm<64,64,64>(sm, a.Wq2b, a.STf2, a.T2b,
                              262144L, 4096L, 262144L, 512, 64, vb - 256);
    } else if constexpr (S == 9) {   // M2p^T = (T2.Wo2p)^T (512)
        gemm_block<64,64,2>(sm, a.T2b, a.Wo2pT, nullptr, a.M2pt,
            512, 512, 512, 512, 1, 1,
            262144L, 0L, 262144L, 0L, 262144L, 0L, 0L, 0L, 0, 1.0f,
            vb & 7, (vb >> 3) & 7, vb >> 6);
    } else {                         // 10: out = o1.M2p + c2p (512, 128^2)
        gemm_block<128,128,0>(sm, a.o1b, a.M2pt, a.c2p, a.out,
            512, 512, 512, 512, 1, 1,
            1048576L, 0L, 262144L, 0L, 1048576L, 0L, 512L, 0L, 1, 1.0f,
            vb & 3, (vb >> 2) & 15, vb >> 6);
    }
}

#define STAGE_KERNEL(NAME, S, SMEM, MINW)                                    \
__global__ __launch_bounds__(256, MINW) void NAME(MA a)                      \
{                                                                            \
    __shared__ __align__(16) unsigned char smem[SMEM];                       \
    run_stage<S>(a, blockIdx.x, smem);                                       \
}

STAGE_KERNEL(ksg0_prep,    0, 16384, 4)
STAGE_KERNEL(ksg1_kv1wo2p, 1, 32768, 4)
STAGE_KERNEL(ksg2_s1t,     2, 32768, 4)
STAGE_KERNEL(ksg3_t1c1,    3, 49152, 4)   // ss_gemm A 16K + B 32K
STAGE_KERNEL(ksg4_m1t,     4, 32768, 4)
STAGE_KERNEL(ksg5_o1,      5, 65536, 2)   // 128^2, BK=64 dbuf
STAGE_KERNEL(ksg6_kv2,     6, 32768, 4)
STAGE_KERNEL(ksg7_s2t,     7, 32768, 4)
STAGE_KERNEL(ksg8_t2c2p,   8, 16384, 4)
STAGE_KERNEL(ksg9_m2pt,    9, 32768, 4)
STAGE_KERNEL(ksg10_out,   10, 65536, 2)

extern "C" void kernel_launch(void* const* d_in, const int* in_sizes, int n_in,
                              void* d_out, int out_size, void* d_ws, size_t ws_size,
                              hipStream_t stream)
{
    MA ma;
    ma.x   = (const float*)d_in[0];
    const float* Wq1 = (const float*)d_in[1];  ma.bq1 = (const float*)d_in[2];
    const float* Wk1 = (const float*)d_in[3];  const float* bk1 = (const float*)d_in[4];
    const float* Wv1 = (const float*)d_in[5];  const float* bv1 = (const float*)d_in[6];
    const float* Wo1 = (const float*)d_in[7];  ma.bo1 = (const float*)d_in[8];
    const float* Wq2 = (const float*)d_in[9];  ma.bq2 = (const float*)d_in[10];
    const float* Wk2 = (const float*)d_in[11]; const float* bk2 = (const float*)d_in[12];
    const float* Wv2 = (const float*)d_in[13]; const float* bv2 = (const float*)d_in[14];
    const float* Wo2 = (const float*)d_in[15]; ma.bo2 = (const float*)d_in[16];
    const float* Wo  = (const float*)d_in[17]; ma.bo  = (const float*)d_in[18];
    ma.out = (float*)d_out;
    (void)in_sizes; (void)n_in; (void)out_size; (void)ws_size;

    __bf16* wb = (__bf16*)d_ws;
    long o = 0;
    ma.xb    = wb + o; o += 1048576;
    ma.Wk1t  = wb + o; o += 524288;
    ma.Wv1t  = wb + o; o += 524288;
    ma.Wq1b  = wb + o; o += 4194304;
    ma.Wo1t  = wb + o; o += 4194304;
    ma.Wk2t  = wb + o; o += 262144;
    ma.Wv2t  = wb + o; o += 262144;
    ma.Wq2b  = wb + o; o += 2097152;
    ma.Wo2b  = wb + o; o += 2097152;   // Wo2 bf16 flat [g][512f][512d]
    ma.Wot   = wb + o; o += 262144;    // Wo^T [512e][512d]
    ma.Ktb   = wb + o; o += 2097152;   // K1^T [g][128][2048]
    ma.Vtb   = wb + o; o += 2097152;
    ma.T1b   = wb + o; o += 4194304;
    ma.M1t   = wb + o; o += 2097152;
    ma.o1b   = wb + o; o += 8388608;
    ma.K2tb  = ma.Ktb;                 // alias: K2^T [g][64][2048]
    ma.V2tb  = ma.Ktb + 1048576;       // alias: V2^T
    ma.T2b   = wb + o; o += 2097152;
    ma.Wo2pT = wb + o; o += 2097152;   // (Wo2@Wo)^T [g][512e][512f]
    ma.M2pt  = wb + o; o += 2097152;
    float* wf = (float*)(wb + o);
    long p = 0;
    ma.STf1 = wf + p; p += 131072;
    ma.STf2 = wf + p; p += 32768;
    ma.kvb1 = wf + p; p += 2048;
    ma.kvb2 = wf + p; p += 1024;
    ma.c1   = wf + p; p += 4096;
    ma.c2p  = wf + p; p += 4096;
    ma.bo2p = wf + p; p += 4096;

    int nd = 0, totB = 0;
    auto add = [&](const float* s, void* d, int R, int C, int Bc, int mode) {
        int blocks;
        long total = (long)Bc * R * C;
        if (mode == 0) blocks = Bc * (R >> 5) * (C >> 5) / 4;      // 4 tiles/blk
        else if (mode == 1) blocks = (int)(total / 4096);          // 16 f/thread
        else if (mode == 4) blocks = (int)((total + 4095) / 4096); // 16 f/thread
        else blocks = (int)((total + 255) / 256);
        ma.pa.p[nd] = PD{s, d, R, C, Bc, mode, blocks};
        ++nd; totB += blocks;
    };
    add(ma.x, ma.xb,   2048, 512, 1, 1);
    add(Wq1,  ma.Wq1b, 512, 128, 64, 1);
    add(Wq2,  ma.Wq2b, 512, 64, 64, 1);
    add(Wo2,  ma.Wo2b, 512, 512, 8, 1);
    add(Wk1,  ma.Wk1t, 512, 128, 8, 0);
    add(Wv1,  ma.Wv1t, 512, 128, 8, 0);
    add(Wo1,  ma.Wo1t, 1024, 512, 8, 0);
    add(Wk2,  ma.Wk2t, 512, 64, 8, 0);
    add(Wv2,  ma.Wv2t, 512, 64, 8, 0);
    add(Wo,   ma.Wot,  512, 512, 1, 0);
    add(bk1,  ma.kvb1,        1, 1024, 1, 2);
    add(bv1,  ma.kvb1 + 1024, 1, 1024, 1, 2);
    add(bk2,  ma.kvb2,        1, 512, 1, 2);
    add(bv2,  ma.kvb2 + 512,  1, 512, 1, 2);
    add(nullptr, ma.STf1, 1, 131072, 1, 4);
    add(nullptr, ma.STf2, 1, 32768, 1, 4);
    ma.pa.n = nd;
    ma.prepTot = totB;

    ksg0_prep   <<<dim3(ma.prepTot), dim3(256), 0, stream>>>(ma);
    ksg1_kv1wo2p<<<dim3(1792), dim3(256), 0, stream>>>(ma);
    ksg2_s1t    <<<dim3(256),  dim3(256), 0, stream>>>(ma);
    ksg3_t1c1   <<<dim3(768),  dim3(256), 0, stream>>>(ma);
    ksg4_m1t    <<<dim3(512),  dim3(256), 0, stream>>>(ma);
    ksg5_o1     <<<dim3(512),  dim3(256), 0, stream>>>(ma);
    ksg6_kv2    <<<dim3(512),  dim3(256), 0, stream>>>(ma);
    ksg7_s2t    <<<dim3(128),  dim3(256), 0, stream>>>(ma);
    ksg8_t2c2p  <<<dim3(768),  dim3(256), 0, stream>>>(ma);
    ksg9_m2pt   <<<dim3(512),  dim3(256), 0, stream>>>(ma);
    ksg10_out   <<<dim3(512),  dim3(256), 0, stream>>>(ma);
}

// Round 11
// 256.716 us; speedup vs baseline: 1.0660x; 1.0298x over previous
//
#include <hip/hip_runtime.h>

// N=2048, D=512, A=64, NQ=8, G1=G2=8, A1=128.
// Algebra (no softmax): ctx = q (K^T V)/sqrt(a) => per-group fold:
//   S[g]=(xWk+bk)^T(xWv+bv)/sqrt(a); M[g]=sum_q Wq S Wo_q; o[g]=x M[g]+c[g];
//   tier2 same; Wo2p[g]=Wo2[g]@Wo precomputed => M2p = T2@Wo2p,
//   c2p = r2@Wo2p + (bo2@Wo + bo).
// R21 (final): lock in the session-best configuration = exact R15 kernel
//   (257.3us measured). Post-R15 probes: gram fold (R16/17, -16us loss),
//   small-first order (R18, neutral), ksplit widening (R19, -14us atomic
//   contention), wide prep (R20, -5us TLP loss on transpose) — all reverted.
//   Structure: 11 serial stages, each below the 41us harness-fill line;
//   residual time is per-stage launch/ramp/drain latency (no saturated
//   pipe; grid-barrier fusion measured at ~58us/barrier in prior session).
// Techniques carried: BK=64 XOR-swizzled 2-phase gemm_block (R15: linear
//   LDS dst + pre-swizzled global src chunk cg=cp^(row&7), same XOR on
//   ds_read -> conflict-free b128 reads; one barrier per 64-K step);
//   ss_gemm single-shot-K (R13: whole K staged, one barrier, ~20 memops
//   in flight); mode-2 swapped-operand transposed store (R14: mfma(B,A)
//   computes C^T natively -> mrow-contiguous stores, no 16x write amp).

typedef __bf16 bf16x8 __attribute__((ext_vector_type(8)));
typedef float  f32x4  __attribute__((ext_vector_type(4)));

struct PD { const float* s; void* d; int R, C, Bc, mode, blocks; };
struct PArgs { PD p[20]; int n; };

struct MA {
    const float *x,*bq1,*bo1,*bq2,*bo2,*bo;
    float* out;
    __bf16 *xb,*Wk1t,*Wv1t,*Wq1b,*Wo1t,*Wk2t,*Wv2t,*Wq2b,*Wo2b,*Wot;
    __bf16 *Ktb,*Vtb,*T1b,*M1t,*o1b,*K2tb,*V2tb,*T2b,*Wo2pT,*M2pt;
    float *STf1,*STf2,*kvb1,*kvb2,*c1,*c2p,*bo2p;
    PArgs pa;
    int prepTot;
};

// ---------------- single-shot-K GEMM (K fits LDS; one barrier) -------------
template<int BM, int BN, int KK>
__device__ __forceinline__ void ss_gemm(void* smv,
    const __bf16* __restrict__ A, const float* __restrict__ Bf,
    __bf16* __restrict__ C, long aG, long bG, long cG, int cD, int cQ, int vb)
{
    constexpr int MT = BM / 32, NT = BN / 32, KS = KK / 32;
    constexpr int ACH = (KK * 2) / 16;
    constexpr int ABYTES = BM * KK * 2;
    constexpr int AITER = ABYTES / 16 / 256;
    constexpr int ROWB = KK * 2;
    constexpr int F4PT = (BN * KK) / 4 / 256;
    constexpr int TPR  = (KK / 4) / F4PT;

    char* smc = (char*)smv;
    int g = vb >> 6, rb = vb & 63;
    A  += g * aG + (long)rb * BM * KK;
    Bf += g * bG;
    C  += g * cG;

    int tid = threadIdx.x, wave = tid >> 6, lane = tid & 63;
    int mrow = lane & 15, quad = lane >> 4;

    #pragma unroll
    for (int i = 0; i < AITER; ++i) {
        int c = tid + i * 256;
        int row = c / ACH, cp = c % ACH;
        int cg = cp ^ (row & 7);
        __builtin_amdgcn_global_load_lds(
            (const __attribute__((address_space(1))) void*)(A + (long)row * KK + cg * 8),
            (__attribute__((address_space(3))) void*)(smc + c * 16),
            16, 0, 0);
    }
    {
        int brow = tid / TPR, bseg = tid % TPR;
        const float4* bsrc = (const float4*)(Bf + (long)brow * KK + bseg * (KK / TPR));
        int cbase = (bseg * (KK / TPR)) >> 3;
        int bx7 = brow & 7;
        char* bls = smc + ABYTES + (long)brow * ROWB;
        #pragma unroll
        for (int j = 0; j < F4PT / 2; ++j) {
            float4 f0 = bsrc[2 * j], f1 = bsrc[2 * j + 1];
            bf16x8 v = {(__bf16)f0.x, (__bf16)f0.y, (__bf16)f0.z, (__bf16)f0.w,
                        (__bf16)f1.x, (__bf16)f1.y, (__bf16)f1.z, (__bf16)f1.w};
            *(bf16x8*)(bls + (((cbase + j) ^ bx7) << 4)) = v;
        }
    }
    __syncthreads();

    int wm = (wave >> 1) * (BM / 2), wn = (wave & 1) * (BN / 2);
    f32x4 acc[MT][NT];
    #pragma unroll
    for (int i = 0; i < MT; ++i)
        #pragma unroll
        for (int j = 0; j < NT; ++j)
            acc[i][j] = f32x4{0.f, 0.f, 0.f, 0.f};

    #pragma unroll
    for (int ks = 0; ks < KS; ++ks) {
        bf16x8 af[MT], bv[NT];
        #pragma unroll
        for (int mt = 0; mt < MT; ++mt) {
            int r = wm + mt * 16 + mrow;
            af[mt] = *(const bf16x8*)(smc + (long)r * ROWB
                        + (((ks * 4 + quad) ^ (r & 7)) << 4));
        }
        #pragma unroll
        for (int nt = 0; nt < NT; ++nt) {
            int r = wn + nt * 16 + mrow;
            bv[nt] = *(const bf16x8*)(smc + ABYTES + (long)r * ROWB
                        + (((ks * 4 + quad) ^ (r & 7)) << 4));
        }
        #pragma unroll
        for (int mt = 0; mt < MT; ++mt)
            #pragma unroll
            for (int nt = 0; nt < NT; ++nt)
                acc[mt][nt] = __builtin_amdgcn_mfma_f32_16x16x32_bf16(
                    af[mt], bv[nt], acc[mt][nt], 0, 0, 0);
    }

    #pragma unroll
    for (int mt = 0; mt < MT; ++mt) {
        #pragma unroll
        for (int r4 = 0; r4 < 4; ++r4) {
            int rl = wm + mt * 16 + quad * 4 + r4;
            int ra = rb * BM + rl;
            int q = ra >> 9, d = ra & 511;
            #pragma unroll
            for (int nt = 0; nt < NT; ++nt) {
                int col = wn + nt * 16 + mrow;
                C[(long)d * cD + q * cQ + col] = (__bf16)acc[mt][nt][r4];
            }
        }
    }
}

// ---------------- bf16 MFMA GEMM block, C = alpha*(A.B^T) (+bias) ----------
// MODE: 0=f32, 1=bf16, 2=bf16 transposed (swapped MFMA operands), 3=f32 atomic.
// BK=64 2-phase XOR-swizzled pipeline (R15).
template<int BM, int BN, int MODE>
__device__ __forceinline__ void gemm_block(void* smv,
    const __bf16* __restrict__ A, const __bf16* __restrict__ B,
    const float* __restrict__ bias, void* __restrict__ Cv,
    int K, int lda, int ldb, int ldc, int divq, int ksplit,
    long aOut, long aIn, long bOut, long bIn, long cOut, long cIn,
    long biasOut, long biasIn, int hasBias, float alpha,
    int bx, int by, int bz)
{
    constexpr int MT = BM / 32, NT = BN / 32;
    constexpr int ROWB = 128;
    constexpr int HALF = (BM + BN) * ROWB;
    constexpr int AOPS = BM * 8 / 256;
    constexpr int BOPS = BN * 8 / 256;

    char* smc = (char*)smv;

    int b  = bz / ksplit, ks = bz - b * ksplit;
    int go = b / divq,  gi = b - go * divq;
    A += go * aOut + gi * aIn;
    B += go * bOut + gi * bIn;
    long cBase = go * cOut + gi * cIn;
    if (hasBias) bias += go * biasOut + gi * biasIn;

    int kChunk = K / ksplit;
    int k0 = ks * kChunk;
    int nT = kChunk / 64;

    int bm = by * BM, bn = bx * BN;
    int tid = threadIdx.x, wave = tid >> 6, lane = tid & 63;
    int wm = (wave >> 1) * (BM / 2), wn = (wave & 1) * (BN / 2);
    int mrow = lane & 15, quad = lane >> 4;

    f32x4 acc[MT][NT];
    #pragma unroll
    for (int i = 0; i < MT; ++i)
        #pragma unroll
        for (int j = 0; j < NT; ++j)
            acc[i][j] = f32x4{0.f, 0.f, 0.f, 0.f};

    auto issueAB = [&](int buf, int kk) {
        char* base = smc + buf * HALF;
        #pragma unroll
        for (int t = 0; t < AOPS; ++t) {
            int c = tid + t * 256;
            int row = c >> 3, cp = c & 7;
            int cg = cp ^ (row & 7);
            __builtin_amdgcn_global_load_lds(
                (const __attribute__((address_space(1))) void*)
                    (A + (long)(bm + row) * lda + kk + cg * 8),
                (__attribute__((address_space(3))) void*)(base + c * 16),
                16, 0, 0);
        }
        char* bbase = base + BM * ROWB;
        #pragma unroll
        for (int t = 0; t < BOPS; ++t) {
            int c = tid + t * 256;
            int row = c >> 3, cp = c & 7;
            int cg = cp ^ (row & 7);
            __builtin_amdgcn_global_load_lds(
                (const __attribute__((address_space(1))) void*)
                    (B + (long)(bn + row) * ldb + kk + cg * 8),
                (__attribute__((address_space(3))) void*)(bbase + c * 16),
                16, 0, 0);
        }
    };

    issueAB(0, k0);
    __syncthreads();

    int cur = 0;
    for (int t = 0; t < nT; ++t) {
        if (t + 1 < nT) issueAB(cur ^ 1, k0 + (t + 1) * 64);

        char* base = smc + cur * HALF;
        #pragma unroll
        for (int k2 = 0; k2 < 2; ++k2) {
            bf16x8 af[MT], bfv[NT];
            #pragma unroll
            for (int mt = 0; mt < MT; ++mt) {
                int r = wm + mt * 16 + mrow;
                af[mt] = *(const bf16x8*)(base + r * ROWB
                            + (((k2 * 4 + quad) ^ (r & 7)) << 4));
            }
            #pragma unroll
            for (int nt = 0; nt < NT; ++nt) {
                int r = wn + nt * 16 + mrow;
                bfv[nt] = *(const bf16x8*)(base + BM * ROWB + r * ROWB
                            + (((k2 * 4 + quad) ^ (r & 7)) << 4));
            }
            #pragma unroll
            for (int mt = 0; mt < MT; ++mt)
                #pragma unroll
                for (int nt = 0; nt < NT; ++nt) {
                    if constexpr (MODE == 2)
                        acc[mt][nt] = __builtin_amdgcn_mfma_f32_16x16x32_bf16(
                            bfv[nt], af[mt], acc[mt][nt], 0, 0, 0);
                    else
                        acc[mt][nt] = __builtin_amdgcn_mfma_f32_16x16x32_bf16(
                            af[mt], bfv[nt], acc[mt][nt], 0, 0, 0);
                }
        }

        __syncthreads();
        cur ^= 1;
    }

    if constexpr (MODE == 2) {
        #pragma unroll
        for (int nt = 0; nt < NT; ++nt) {
            #pragma unroll
            for (int r = 0; r < 4; ++r) {
                int ci = bn + wn + nt * 16 + quad * 4 + r;
                #pragma unroll
                for (int mt = 0; mt < MT; ++mt) {
                    int mi = bm + wm + mt * 16 + mrow;
                    float v = acc[mt][nt][r] * alpha;
                    if (hasBias) v += bias[ci];
                    ((__bf16*)Cv)[cBase + (long)ci * ldc + mi] = (__bf16)v;
                }
            }
        }
    } else {
        #pragma unroll
        for (int mt = 0; mt < MT; ++mt) {
            #pragma unroll
            for (int r = 0; r < 4; ++r) {
                int row = bm + wm + mt * 16 + quad * 4 + r;
                #pragma unroll
                for (int nt = 0; nt < NT; ++nt) {
                    int col = bn + wn + nt * 16 + mrow;
                    float v = acc[mt][nt][r] * alpha;
                    if (hasBias) v += bias[col];
                    if constexpr (MODE == 0)
                        ((float*)Cv)[cBase + (long)row * ldc + col] = v;
                    else if constexpr (MODE == 1)
                        ((__bf16*)Cv)[cBase + (long)row * ldc + col] = (__bf16)v;
                    else
                        atomicAdd(&((float*)Cv)[cBase + (long)row * ldc + col], v);
                }
            }
        }
    }
}

// ---------------- prep block: converts/transposes/zeros ---------------------
__device__ __forceinline__ void prep_block(const PArgs& a, int bid, void* smv)
{
    int i = 0;
    while (i < a.n && bid >= a.p[i].blocks) { bid -= a.p[i].blocks; ++i; }
    if (i >= a.n) return;
    PD d = a.p[i];
    int t = threadIdx.x;
    if (d.mode == 0) {
        float (*tile)[33] = (float(*)[33])smv;
        int tC = d.C >> 5, tR = d.R >> 5;
        int batch = bid / (tC * tR), rem = bid - batch * (tC * tR);
        int tyo = rem / tC, txo = rem - tyo * tC;
        const float* src = d.s + (long)batch * d.R * d.C;
        __bf16* dst = (__bf16*)d.d + (long)batch * d.R * d.C;
        int tx = t & 31, ty = t >> 5;
        int r0 = tyo * 32, c0 = txo * 32;
        #pragma unroll
        for (int u = 0; u < 4; ++u)
            tile[ty + 8 * u][tx] = src[(long)(r0 + ty + 8 * u) * d.C + c0 + tx];
        __syncthreads();
        #pragma unroll
        for (int u = 0; u < 4; ++u)
            dst[(long)(c0 + ty + 8 * u) * d.R + r0 + tx] = (__bf16)tile[tx][ty + 8 * u];
    } else if (d.mode == 1) {
        long idx = ((long)bid * 256 + t) * 4;
        long total = (long)d.Bc * d.R * d.C;
        if (idx < total) {
            float4 f = *(const float4*)(d.s + idx);
            __bf16* o = (__bf16*)d.d + idx;
            o[0] = (__bf16)f.x; o[1] = (__bf16)f.y;
            o[2] = (__bf16)f.z; o[3] = (__bf16)f.w;
        }
    } else {
        long idx = (long)bid * 256 + t;
        long total = (long)d.Bc * d.R * d.C;
        if (idx < total) {
            float* o = (float*)d.d;
            if (d.mode == 2) o[idx] = d.s[idx];
            else             o[idx] = 0.f;
        }
    }
}

// ---------------- small block: c-vector from S^T (fp32) --------------------
__device__ __forceinline__ void small_block(void* smv,
    const float* __restrict__ STf, const float* __restrict__ bq,
    const __bf16* __restrict__ WoT, const float* __restrict__ boA,
    float* __restrict__ cOut, int ad, int F, long wG, int bid)
{
    int tid = threadIdx.x;
    float* rL  = (float*)smv;
    float* red = (float*)((char*)smv + 4096);
    int g = bid >> 5, slice = bid & 31;
    int nq = F / ad;
    const float* Sg = STf + (long)g * ad * ad;
    for (int f = tid; f < F; f += 256) {
        int q = f / ad, aa = f - q * ad;
        const float* bv = bq + (long)(g * nq + q) * ad;
        const float* Sa = Sg + (long)aa * ad;
        float s = 0.f;
        for (int c = 0; c < ad; c += 4) {
            float4 b4 = *(const float4*)(bv + c);
            float4 s4 = *(const float4*)(Sa + c);
            s += b4.x * s4.x + b4.y * s4.y + b4.z * s4.z + b4.w * s4.w;
        }
        rL[f] = s;
    }
    __syncthreads();
    int dl = tid & 15, fs = tid >> 4;
    int d = slice * 16 + dl;
    int fchunk = F >> 4;
    const __bf16* wrow = WoT + (long)g * wG + (long)d * F;
    float s = 0.f;
    for (int f0 = fs * fchunk; f0 < (fs + 1) * fchunk; f0 += 8) {
        bf16x8 w = *(const bf16x8*)(wrow + f0);
        s += rL[f0]     * (float)w[0] + rL[f0 + 1] * (float)w[1]
           + rL[f0 + 2] * (float)w[2] + rL[f0 + 3] * (float)w[3]
           + rL[f0 + 4] * (float)w[4] + rL[f0 + 5] * (float)w[5]
           + rL[f0 + 6] * (float)w[6] + rL[f0 + 7] * (float)w[7];
    }
    red[tid] = s;
    __syncthreads();
    if (fs == 0) {
        float tsum = s;
        #pragma unroll
        for (int u = 1; u < 16; ++u) tsum += red[u * 16 + dl];
        cOut[(long)g * 512 + d] = boA[(long)g * 512 + d] + tsum;
    }
}

// outp[g][d] = bias[d] + sum_f v[g][f] * WT[d][f]   (F=512)
__device__ __forceinline__ void vecmat_block(void* smv,
    const float* __restrict__ v, const __bf16* __restrict__ WT,
    const float* __restrict__ bias, float* __restrict__ outp, int g, int slice)
{
    float* red2 = (float*)smv;
    int tid = threadIdx.x;
    int dl = tid & 15, fs = tid >> 4;
    int d = slice * 16 + dl;
    const float* vg = v + (long)g * 512;
    const __bf16* wrow = WT + (long)d * 512;
    float s = 0.f;
    for (int f0 = fs * 32; f0 < (fs + 1) * 32; f0 += 8) {
        bf16x8 w = *(const bf16x8*)(wrow + f0);
        s += vg[f0]     * (float)w[0] + vg[f0 + 1] * (float)w[1]
           + vg[f0 + 2] * (float)w[2] + vg[f0 + 3] * (float)w[3]
           + vg[f0 + 4] * (float)w[4] + vg[f0 + 5] * (float)w[5]
           + vg[f0 + 6] * (float)w[6] + vg[f0 + 7] * (float)w[7];
    }
    red2[tid] = s;
    __syncthreads();
    if (fs == 0) {
        float tsum = s;
        #pragma unroll
        for (int u = 1; u < 16; ++u) tsum += red2[u * 16 + dl];
        outp[(long)g * 512 + d] = bias[d] + tsum;
    }
}

// ---------------- stages (compile-time dispatch) ----------------------------
template<int S>
__device__ __forceinline__ void run_stage(const MA& a, int vb, void* sm)
{
    const float isa1 = 0.08838834764831845f;  // 1/sqrt(128)
    if constexpr (S == 0) {
        prep_block(a.pa, vb, sm);
    } else if constexpr (S == 1) {   // KV1 (1024) | Wo2p (512) | bo2p (256)
        if (vb < 1024)
            gemm_block<64,64,2>(sm, a.xb, a.Wk1t, a.kvb1, a.Ktb,
                512, 512, 512, 2048, 1, 1,
                0L, 0L, 65536L, 0L, 262144L, 0L, 128L, 0L, 1, 1.0f,
                vb & 1, (vb >> 1) & 31, vb >> 6);
        else if (vb < 1536) {
            int v = vb - 1024;
            gemm_block<64,64,2>(sm, a.Wo2b, a.Wot, nullptr, a.Wo2pT,
                512, 512, 512, 512, 1, 1,
                262144L, 0L, 0L, 0L, 262144L, 0L, 0L, 0L, 0, 1.0f,
                v & 7, (v >> 3) & 7, v >> 6);
        } else {
            int v = vb - 1536;
            vecmat_block(sm, a.bo2, a.Wot, a.bo, a.bo2p, v & 7, v >> 3);
        }
    } else if constexpr (S == 2) {   // S1^T split-K x8 atomic (256)
        gemm_block<64,64,3>(sm, a.Vtb, a.Ktb, nullptr, a.STf1,
            2048, 2048, 2048, 128, 1, 8,
            262144L, 0L, 262144L, 0L, 16384L, 0L, 0L, 0L, 0, isa1,
            vb & 1, (vb >> 1) & 1, vb >> 2);
    } else if constexpr (S == 3) {   // T1 ss_gemm (512) | c1 (256)
        if (vb < 512)
            ss_gemm<64,128,128>(sm, a.Wq1b, a.STf1, a.T1b,
                                524288L, 16384L, 524288L, 1024, 128, vb);
        else
            small_block(sm, a.STf1, a.bq1, a.Wo1t, a.bo1, a.c1,
                        128, 1024, 524288L, vb - 512);
    } else if constexpr (S == 4) {   // M1^T (512)
        gemm_block<64,64,2>(sm, a.T1b, a.Wo1t, nullptr, a.M1t,
            1024, 1024, 1024, 512, 1, 1,
            524288L, 0L, 524288L, 0L, 262144L, 0L, 0L, 0L, 0, 1.0f,
            vb & 7, (vb >> 3) & 7, vb >> 6);
    } else if constexpr (S == 5) {   // o1 = x.M1 + c1 (512, 128^2)
        gemm_block<128,128,1>(sm, a.xb, a.M1t, a.c1, a.o1b,
            512, 512, 512, 512, 1, 1,
            0L, 0L, 262144L, 0L, 1048576L, 0L, 512L, 0L, 1, 1.0f,
            vb & 3, (vb >> 2) & 15, vb >> 6);
    } else if constexpr (S == 6) {   // KV2 fused (512)
        gemm_block<64,64,2>(sm, a.o1b, a.Wk2t, a.kvb2, a.K2tb,
            512, 512, 512, 2048, 8, 1,
            0L, 1048576L, 262144L, 32768L, 1048576L, 131072L, 512L, 64L,
            1, 1.0f, 0, vb & 31, vb >> 5);
    } else if constexpr (S == 7) {   // S2^T split-K x16 atomic (128)
        gemm_block<64,64,3>(sm, a.V2tb, a.K2tb, nullptr, a.STf2,
            2048, 2048, 2048, 64, 1, 16,
            131072L, 0L, 131072L, 0L, 4096L, 0L, 0L, 0L, 0, 0.125f,
            0, 0, vb);
    } else if constexpr (S == 8) {   // T2 ss_gemm (512) | c2p (256)
        if (vb < 512)
            ss_gemm<64,64,64>(sm, a.Wq2b, a.STf2, a.T2b,
                              262144L, 4096L, 262144L, 512, 64, vb);
        else
            small_block(sm, a.STf2, a.bq2, a.Wo2pT, a.bo2p, a.c2p,
                        64, 512, 262144L, vb - 512);
    } else if constexpr (S == 9) {   // M2p^T = (T2.Wo2p)^T (512)
        gemm_block<64,64,2>(sm, a.T2b, a.Wo2pT, nullptr, a.M2pt,
            512, 512, 512, 512, 1, 1,
            262144L, 0L, 262144L, 0L, 262144L, 0L, 0L, 0L, 0, 1.0f,
            vb & 7, (vb >> 3) & 7, vb >> 6);
    } else {                         // 10: out = o1.M2p + c2p (512, 128^2)
        gemm_block<128,128,0>(sm, a.o1b, a.M2pt, a.c2p, a.out,
            512, 512, 512, 512, 1, 1,
            1048576L, 0L, 262144L, 0L, 1048576L, 0L, 512L, 0L, 1, 1.0f,
            vb & 3, (vb >> 2) & 15, vb >> 6);
    }
}

#define STAGE_KERNEL(NAME, S, SMEM, MINW)                                    \
__global__ __launch_bounds__(256, MINW) void NAME(MA a)                      \
{                                                                            \
    __shared__ __align__(16) unsigned char smem[SMEM];                       \
    run_stage<S>(a, blockIdx.x, smem);                                       \
}

STAGE_KERNEL(ksg0_prep,    0, 16384, 4)
STAGE_KERNEL(ksg1_kv1wo2p, 1, 32768, 4)
STAGE_KERNEL(ksg2_s1t,     2, 32768, 4)
STAGE_KERNEL(ksg3_t1c1,    3, 49152, 4)   // ss_gemm A 16K + B 32K
STAGE_KERNEL(ksg4_m1t,     4, 32768, 4)
STAGE_KERNEL(ksg5_o1,      5, 65536, 2)   // 128^2, BK=64 dbuf
STAGE_KERNEL(ksg6_kv2,     6, 32768, 4)
STAGE_KERNEL(ksg7_s2t,     7, 32768, 4)
STAGE_KERNEL(ksg8_t2c2p,   8, 16384, 4)
STAGE_KERNEL(ksg9_m2pt,    9, 32768, 4)
STAGE_KERNEL(ksg10_out,   10, 65536, 2)

extern "C" void kernel_launch(void* const* d_in, const int* in_sizes, int n_in,
                              void* d_out, int out_size, void* d_ws, size_t ws_size,
                              hipStream_t stream)
{
    MA ma;
    ma.x   = (const float*)d_in[0];
    const float* Wq1 = (const float*)d_in[1];  ma.bq1 = (const float*)d_in[2];
    const float* Wk1 = (const float*)d_in[3];  const float* bk1 = (const float*)d_in[4];
    const float* Wv1 = (const float*)d_in[5];  const float* bv1 = (const float*)d_in[6];
    const float* Wo1 = (const float*)d_in[7];  ma.bo1 = (const float*)d_in[8];
    const float* Wq2 = (const float*)d_in[9];  ma.bq2 = (const float*)d_in[10];
    const float* Wk2 = (const float*)d_in[11]; const float* bk2 = (const float*)d_in[12];
    const float* Wv2 = (const float*)d_in[13]; const float* bv2 = (const float*)d_in[14];
    const float* Wo2 = (const float*)d_in[15]; ma.bo2 = (const float*)d_in[16];
    const float* Wo  = (const float*)d_in[17]; ma.bo  = (const float*)d_in[18];
    ma.out = (float*)d_out;
    (void)in_sizes; (void)n_in; (void)out_size; (void)ws_size;

    __bf16* wb = (__bf16*)d_ws;
    long o = 0;
    ma.xb    = wb + o; o += 1048576;
    ma.Wk1t  = wb + o; o += 524288;
    ma.Wv1t  = wb + o; o += 524288;
    ma.Wq1b  = wb + o; o += 4194304;
    ma.Wo1t  = wb + o; o += 4194304;
    ma.Wk2t  = wb + o; o += 262144;
    ma.Wv2t  = wb + o; o += 262144;
    ma.Wq2b  = wb + o; o += 2097152;
    ma.Wo2b  = wb + o; o += 2097152;   // Wo2 bf16 flat [g][512f][512d]
    ma.Wot   = wb + o; o += 262144;    // Wo^T [512e][512d]
    ma.Ktb   = wb + o; o += 2097152;   // K1^T [g][128][2048]
    ma.Vtb   = wb + o; o += 2097152;
    ma.T1b   = wb + o; o += 4194304;
    ma.M1t   = wb + o; o += 2097152;
    ma.o1b   = wb + o; o += 8388608;
    ma.K2tb  = ma.Ktb;                 // alias: K2^T [g][64][2048]
    ma.V2tb  = ma.Ktb + 1048576;       // alias: V2^T
    ma.T2b   = wb + o; o += 2097152;
    ma.Wo2pT = wb + o; o += 2097152;   // (Wo2@Wo)^T [g][512e][512f]
    ma.M2pt  = wb + o; o += 2097152;
    float* wf = (float*)(wb + o);
    long p = 0;
    ma.STf1 = wf + p; p += 131072;
    ma.STf2 = wf + p; p += 32768;
    ma.kvb1 = wf + p; p += 2048;
    ma.kvb2 = wf + p; p += 1024;
    ma.c1   = wf + p; p += 4096;
    ma.c2p  = wf + p; p += 4096;
    ma.bo2p = wf + p; p += 4096;

    int nd = 0, totB = 0;
    auto add = [&](const float* s, void* d, int R, int C, int Bc, int mode) {
        int blocks;
        long total = (long)Bc * R * C;
        if (mode == 0) blocks = Bc * (R >> 5) * (C >> 5);
        else if (mode == 1) blocks = (int)(total / 1024);
        else blocks = (int)((total + 255) / 256);
        ma.pa.p[nd] = PD{s, d, R, C, Bc, mode, blocks};
        ++nd; totB += blocks;
    };
    add(ma.x, ma.xb,   2048, 512, 1, 1);
    add(Wq1,  ma.Wq1b, 512, 128, 64, 1);
    add(Wq2,  ma.Wq2b, 512, 64, 64, 1);
    add(Wo2,  ma.Wo2b, 512, 512, 8, 1);
    add(Wk1,  ma.Wk1t, 512, 128, 8, 0);
    add(Wv1,  ma.Wv1t, 512, 128, 8, 0);
    add(Wo1,  ma.Wo1t, 1024, 512, 8, 0);
    add(Wk2,  ma.Wk2t, 512, 64, 8, 0);
    add(Wv2,  ma.Wv2t, 512, 64, 8, 0);
    add(Wo,   ma.Wot,  512, 512, 1, 0);
    add(bk1,  ma.kvb1,        1, 1024, 1, 2);
    add(bv1,  ma.kvb1 + 1024, 1, 1024, 1, 2);
    add(bk2,  ma.kvb2,        1, 512, 1, 2);
    add(bv2,  ma.kvb2 + 512,  1, 512, 1, 2);
    add(nullptr, ma.STf1, 1, 131072, 1, 4);
    add(nullptr, ma.STf2, 1, 32768, 1, 4);
    ma.pa.n = nd;
    ma.prepTot = totB;

    ksg0_prep   <<<dim3(ma.prepTot), dim3(256), 0, stream>>>(ma);
    ksg1_kv1wo2p<<<dim3(1792), dim3(256), 0, stream>>>(ma);
    ksg2_s1t    <<<dim3(256),  dim3(256), 0, stream>>>(ma);
    ksg3_t1c1   <<<dim3(768),  dim3(256), 0, stream>>>(ma);
    ksg4_m1t    <<<dim3(512),  dim3(256), 0, stream>>>(ma);
    ksg5_o1     <<<dim3(512),  dim3(256), 0, stream>>>(ma);
    ksg6_kv2    <<<dim3(512),  dim3(256), 0, stream>>>(ma);
    ksg7_s2t    <<<dim3(128),  dim3(256), 0, stream>>>(ma);
    ksg8_t2c2p  <<<dim3(768),  dim3(256), 0, stream>>>(ma);
    ksg9_m2pt   <<<dim3(512),  dim3(256), 0, stream>>>(ma);
    ksg10_out   <<<dim3(512),  dim3(256), 0, stream>>>(ma);
}